// Round 3
// baseline (368.991 us; speedup 1.0000x reference)
//
#include <hip/hip_runtime.h>
#include <hip/hip_bf16.h>

// Lukasiewicz t-norm feature expansion, write-BW-bound (~365 MB out).
//   out[:, 0:16]    = x
//   out[:, 16:136]  = max(x[a]+x[b] - 1, 0)        (a,b)   lex combos of 16
//   out[:, 136:696] = max(x[a]+x[b]+x[c] - 2, 0)   (a,b,c) lex combos of 16
//
// R3: plain (non-NT) dwordx4 stores, pure-linear store addressing
// (r*696+4*c4 == 4*i so each 16-row tile is one contiguous, 256B-aligned
// 44.5KB stream), branchless r/c4 increment, fully unrolled quad loop.
// R2 (NT stores, magic-div) ran the kernel at ~2.6 TB/s effective.

#define NCOLS 696
#define NC4   174          // NCOLS / 4
#define RPT   16           // rows per tile; 131072 % 16 == 0, no tail
#define NQ    (RPT * NC4)  // 2784 float4 stores per tile

typedef float v4f __attribute__((ext_vector_type(4)));

struct ColTab { unsigned int v[NCOLS]; };

// Packed per-column descriptor: a[4:0] | b[9:5] | c[14:10] | bias[16:15]
// index 16 -> zero slot. Order matches itertools.combinations (lex).
constexpr ColTab make_tab() {
    ColTab t{};
    int k = 0;
    for (int a = 0; a < 16; ++a)
        t.v[k++] = (unsigned)a | (16u << 5) | (16u << 10);
    for (int a = 0; a < 16; ++a)
        for (int b = a + 1; b < 16; ++b)
            t.v[k++] = (unsigned)a | ((unsigned)b << 5) | (16u << 10) | (1u << 15);
    for (int a = 0; a < 16; ++a)
        for (int b = a + 1; b < 16; ++b)
            for (int c = b + 1; c < 16; ++c)
                t.v[k++] = (unsigned)a | ((unsigned)b << 5) | ((unsigned)c << 10) | (2u << 15);
    return t;
}

__constant__ ColTab g_tab = make_tab();

__device__ __forceinline__ float tnorm(const float* __restrict__ xr, unsigned v) {
    return fmaxf(xr[v & 31u] + xr[(v >> 5) & 31u] + xr[(v >> 10) & 31u]
                 - (float)((v >> 15) & 3u), 0.0f);
}

__global__ __launch_bounds__(256) void luk_kernel(const float* __restrict__ x,
                                                  float* __restrict__ out,
                                                  int ntiles) {
    // 16 rows * (16 vals + zero slot), stride 17: conflict-free (17 distinct
    // banks per row region; same-address reads broadcast).
    __shared__ float xl[RPT * 17];
    const int t = threadIdx.x;
    const uint4* __restrict__ tab4 = reinterpret_cast<const uint4*>(g_tab.v);

    // Starting (r, c4) for i0 = t (t < 256 < 2*174 so r0 in {0,1}).
    const int r0  = (t >= NC4) ? 1 : 0;
    const int c40 = t - r0 * NC4;

    for (int tile = blockIdx.x; tile < ntiles; tile += gridDim.x) {
        const int row0 = tile * RPT;

        // cooperative coalesced load: 256 consecutive floats (16 rows x 16)
        xl[(t >> 4) * 17 + (t & 15)] = x[(size_t)row0 * 16 + t];
        if (t < RPT) xl[t * 17 + 16] = 0.0f;
        __syncthreads();

        // Tile output is contiguous: quad i lives at tile_base4 + i.
        // tile_base byte offset = tile * 44544 (multiple of 256B).
        v4f* __restrict__ dst4 = reinterpret_cast<v4f*>(out + (size_t)row0 * NCOLS);

        int r = r0, c4 = c40;
        #pragma unroll
        for (int u = 0; u < 11; ++u) {
            const int i = t + u * 256;
            if (i < NQ) {
                const uint4 tv = tab4[c4];
                const float* __restrict__ xr = &xl[r * 17];
                v4f o;
                o.x = tnorm(xr, tv.x);
                o.y = tnorm(xr, tv.y);
                o.z = tnorm(xr, tv.z);
                o.w = tnorm(xr, tv.w);
                dst4[i] = o;
            }
            // advance by 256 quads: +1 row +82 quads, wrap at most once
            c4 += 256 - NC4;
            r  += 1;
            if (c4 >= NC4) { c4 -= NC4; r += 1; }
        }
        __syncthreads();   // xl reused next tile
    }
}

extern "C" void kernel_launch(void* const* d_in, const int* in_sizes, int n_in,
                              void* d_out, int out_size, void* d_ws, size_t ws_size,
                              hipStream_t stream) {
    const float* x = (const float*)d_in[0];
    float* out = (float*)d_out;
    const int nrows  = in_sizes[0] / 16;           // 131072
    const int ntiles = nrows / RPT;                // 8192, exact
    const int blocks = ntiles < 2048 ? ntiles : 2048;  // 8 blocks/CU
    luk_kernel<<<blocks, 256, 0, stream>>>(x, out, ntiles);
}